// Round 2
// baseline (633.081 us; speedup 1.0000x reference)
//
#include <hip/hip_runtime.h>
#include <hip/hip_bf16.h>

#define NN 100000
#define NE 1600000
#define HID 64
#define SCAN_BS 256
#define NBLK ((NN + SCAN_BS - 1) / SCAN_BS)   // 391

typedef float f32x4 __attribute__((ext_vector_type(4)));
typedef short bf16x8 __attribute__((ext_vector_type(8)));

__device__ __forceinline__ float bflo(unsigned u) { return __uint_as_float(u << 16); }
__device__ __forceinline__ float bfhi(unsigned u) { return __uint_as_float(u & 0xffff0000u); }
__device__ __forceinline__ unsigned short f2bf(float f) {
    __hip_bfloat16 h = (__hip_bfloat16)f;
    return *(unsigned short*)&h;
}

// ---------- x -> bf16 ----------
__global__ void xcast(const float* __restrict__ in, unsigned short* __restrict__ out, int n4) {
    int i = blockIdx.x * blockDim.x + threadIdx.x;
    if (i >= n4) return;
    float4 v = ((const float4*)in)[i];
    ushort4 o;
    o.x = f2bf(v.x); o.y = f2bf(v.y); o.z = f2bf(v.z); o.w = f2bf(v.w);
    ((ushort4*)out)[i] = o;
}

// ---------- CSR build ----------
__global__ void count_kernel(const int* __restrict__ dst, int* __restrict__ degI, int nE) {
    int e = blockIdx.x * blockDim.x + threadIdx.x;
    if (e < nE) atomicAdd(&degI[dst[e]], 1);
}

__global__ void scan1_kernel(const int* __restrict__ degI, int* __restrict__ rowtmp,
                             int* __restrict__ blockSum) {
    __shared__ int tmp[SCAN_BS];
    int t = threadIdx.x;
    int i = blockIdx.x * SCAN_BS + t;
    int d = (i < NN) ? degI[i] : 0;
    tmp[t] = d;
    __syncthreads();
    for (int off = 1; off < SCAN_BS; off <<= 1) {
        int v = (t >= off) ? tmp[t - off] : 0;
        __syncthreads();
        tmp[t] += v;
        __syncthreads();
    }
    if (i < NN) rowtmp[i] = tmp[t] - d;
    if (t == SCAN_BS - 1) blockSum[blockIdx.x] = tmp[t];
}

__global__ void scan2_kernel(const int* __restrict__ blockSum, int* __restrict__ blockOff, int n) {
    __shared__ int tmp[512];
    int t = threadIdx.x;
    tmp[t] = (t < n) ? blockSum[t] : 0;
    __syncthreads();
    for (int off = 1; off < 512; off <<= 1) {
        int v = (t >= off) ? tmp[t - off] : 0;
        __syncthreads();
        tmp[t] += v;
        __syncthreads();
    }
    if (t < n) blockOff[t] = (t == 0) ? 0 : tmp[t - 1];
}

__global__ void scan3_kernel(const int* __restrict__ rowtmp, const int* __restrict__ blockOff,
                             int* __restrict__ row_ptr) {
    int i = blockIdx.x * SCAN_BS + threadIdx.x;
    if (i < NN) row_ptr[i] = rowtmp[i] + blockOff[blockIdx.x];
}

__global__ void fill_kernel(const int* __restrict__ src, const int* __restrict__ dst,
                            const int* __restrict__ row_ptr, int* __restrict__ cursor,
                            int* __restrict__ csr_src, int nE) {
    int e = blockIdx.x * blockDim.x + threadIdx.x;
    if (e >= nE) return;
    int d = dst[e];
    int pos = atomicAdd(&cursor[d], 1);
    csr_src[row_ptr[d] + pos] = src[e];
}

// ---------- pure gather/mean (one wave per node, shuffle reduce, no LDS) ----------
template <int IN>
__launch_bounds__(256)
__global__ void aggregate(const int* __restrict__ row_ptr, const int* __restrict__ degI,
                          const int* __restrict__ csr_src,
                          const unsigned short* __restrict__ hin,
                          float* __restrict__ mout) {
    constexpr int LPE = IN / 4;            // lanes per edge (uint2 = 4 bf16 each)
    constexpr int SPLIT = 64 / LPE;        // edges in flight per wave
    constexpr int UN = (SPLIT >= 8) ? 2 : 4;
    int g = threadIdx.x >> 6;
    int lane = threadIdx.x & 63;
    int node = blockIdx.x * 4 + g;         // grid sized so node < NN always
    int lane_p = lane & (LPE - 1);
    int sub = lane / LPE;

    float a0 = 0.f, a1 = 0.f, a2 = 0.f, a3 = 0.f;
    int start = row_ptr[node];
    int dg = degI[node];
    const int* cs = csr_src + start;

    int e = sub;
    for (; e + SPLIT * (UN - 1) < dg; e += SPLIT * UN) {
        int sidx[UN];
#pragma unroll
        for (int j = 0; j < UN; ++j) sidx[j] = cs[e + SPLIT * j];
        uint2 u[UN];
#pragma unroll
        for (int j = 0; j < UN; ++j)
            u[j] = *(const uint2*)(hin + (size_t)sidx[j] * IN + 4 * lane_p);
#pragma unroll
        for (int j = 0; j < UN; ++j) {
            a0 += bflo(u[j].x); a1 += bfhi(u[j].x);
            a2 += bflo(u[j].y); a3 += bfhi(u[j].y);
        }
    }
    for (; e < dg; e += SPLIT) {
        uint2 u = *(const uint2*)(hin + (size_t)cs[e] * IN + 4 * lane_p);
        a0 += bflo(u.x); a1 += bfhi(u.x);
        a2 += bflo(u.y); a3 += bfhi(u.y);
    }

    // reduce across the SPLIT sub-groups (lanes LPE apart and up)
#pragma unroll
    for (int m = LPE; m < 64; m <<= 1) {
        a0 += __shfl_xor(a0, m);
        a1 += __shfl_xor(a1, m);
        a2 += __shfl_xor(a2, m);
        a3 += __shfl_xor(a3, m);
    }
    if (sub == 0) {
        float r = 1.0f / fmaxf((float)dg, 1.0f);
        float4 v;
        v.x = a0 * r; v.y = a1 * r; v.z = a2 * r; v.w = a3 * r;
        *(float4*)(mout + (size_t)node * IN + 4 * lane_p) = v;
    }
}

// ---------- weight prep: f32 [K][64] -> packed bf16 hi/lo B-fragments ----------
// layout per matrix: [fi = ks*4+nt][hl][lane][8]  (8 shorts = one uint4 per lane)
// B frag element j of lane l: W[k = ks*32 + (l>>4)*8 + j][n = nt*16 + (l&15)]
__global__ void wprep(const float* __restrict__ Wl0, const float* __restrict__ Wr0,
                      const float* __restrict__ Wl1, const float* __restrict__ Wr1,
                      const float* __restrict__ Wl2, const float* __restrict__ Wr2,
                      const float* __restrict__ W1, unsigned short* __restrict__ out) {
    int b = blockIdx.x;
    int mid, local;
    if (b < 2) { mid = b; local = 0; }                  // K=32 matrices: 1 block each
    else { mid = 2 + (b - 2) / 2; local = (b - 2) & 1; } // K=64 matrices: 2 blocks each
    const float* Ws[8] = {Wl0, Wr0, Wl1, Wr1, Wl2, Wr2, W1, W1 + 64 * 64};
    const int offs[8] = {0, 4096, 8192, 16384, 24576, 32768, 40960, 49152};
    const float* W = Ws[mid];
    int e = local * 256 + threadIdx.x;   // entry = (ks*4+nt)*64 + lane
    int lane = e & 63;
    int fi = e >> 6;                     // ks*4 + nt
    int ks = fi >> 2, nt = fi & 3;
    int lg = lane >> 4, col = lane & 15;
    unsigned short hi[8], lo[8];
#pragma unroll
    for (int j = 0; j < 8; ++j) {
        float w = W[(ks * 32 + lg * 8 + j) * 64 + nt * 16 + col];
        unsigned short h = f2bf(w);
        hi[j] = h;
        lo[j] = f2bf(w - bflo(h));
    }
    unsigned short* dh = out + offs[mid] + ((size_t)(fi * 2 + 0) * 64 + lane) * 8;
    unsigned short* dl = out + offs[mid] + ((size_t)(fi * 2 + 1) * 64 + lane) * 8;
#pragma unroll
    for (int j = 0; j < 8; ++j) { dh[j] = hi[j]; dl[j] = lo[j]; }
}

// ---------- edge-predictor weight prep ----------
// we_pk: A-frags (16x16x32) of [64 feat x 32 K] matrix for z1^T = Wpk @ ea_pk:
//   K rows 0..7 = W1e_hi^T, 8..15 = W1e_hi^T, 16..23 = W1e_lo^T, 24 = b1_hi, 25 = b1_lo.
//   entry (mt*64+lane)*8: row f = mt*16 + (lane&15), k = (lane>>4)*8 + j.
// w2h_pk/w2l_pk: A-frags (half-filled 16x16x32, j<4 used) of W2^T [32 x 64(+bias)]:
//   entry ((mt2*NKS+ks)*64+lane)*8: c = mt2*16+(lane&15); j<4 -> W2[ks*16+(lane>>4)*4+j][c].
//   w2h ks==4 = bias tile: lg==0: j0=b2_hi[c], j1=b2_lo[c].
__global__ void wprep2(const float* __restrict__ W1, const float* __restrict__ b1,
                       const float* __restrict__ W2, const float* __restrict__ b2,
                       unsigned short* __restrict__ we_pk,
                       unsigned short* __restrict__ w2h_pk,
                       unsigned short* __restrict__ w2l_pk) {
    int t = threadIdx.x;          // 256 threads, 1 block
    const float* W1e = W1 + 128 * 64;
    // Part A: we_pk (4 mt x 64 lanes)
    {
        int mt = t >> 6, lane = t & 63;
        int ar = lane & 15, lg = lane >> 4;
        int f = mt * 16 + ar;
        unsigned short v[8];
#pragma unroll
        for (int j = 0; j < 8; ++j) {
            if (lg <= 1) {
                v[j] = f2bf(W1e[j * 64 + f]);
            } else if (lg == 2) {
                float w = W1e[j * 64 + f];
                unsigned short h = f2bf(w);
                v[j] = f2bf(w - bflo(h));
            } else {
                if (j == 0) v[j] = f2bf(b1[f]);
                else if (j == 1) {
                    float bb = b1[f];
                    unsigned short h = f2bf(bb);
                    v[j] = f2bf(bb - bflo(h));
                } else v[j] = 0;
            }
        }
        unsigned short* o = we_pk + (size_t)t * 8;
        for (int j = 0; j < 8; ++j) o[j] = v[j];
    }
    // Part B: w2h_pk (2 mt2 x 5 ks x 64 lanes = 640 entries)
    for (int i = t; i < 640; i += 256) {
        int mt2 = i / 320, rem = i % 320;
        int ks = rem >> 6, lane = rem & 63;
        int ar = lane & 15, lg = lane >> 4;
        int c = mt2 * 16 + ar;
        unsigned short v[8] = {0, 0, 0, 0, 0, 0, 0, 0};
        if (ks < 4) {
            for (int j = 0; j < 4; ++j)
                v[j] = f2bf(W2[(ks * 16 + lg * 4 + j) * 32 + c]);
        } else if (lg == 0) {
            float bb = b2[c];
            unsigned short h = f2bf(bb);
            v[0] = h;
            v[1] = f2bf(bb - bflo(h));
        }
        unsigned short* o = w2h_pk + (size_t)i * 8;
        for (int j = 0; j < 8; ++j) o[j] = v[j];
    }
    // Part C: w2l_pk (2 mt2 x 4 ks x 64 lanes = 512 entries)
    for (int i = t; i < 512; i += 256) {
        int mt2 = i / 256, rem = i % 256;
        int ks = rem >> 6, lane = rem & 63;
        int ar = lane & 15, lg = lane >> 4;
        int c = mt2 * 16 + ar;
        unsigned short v[8] = {0, 0, 0, 0, 0, 0, 0, 0};
        for (int j = 0; j < 4; ++j) {
            float w = W2[(ks * 16 + lg * 4 + j) * 32 + c];
            unsigned short h = f2bf(w);
            v[j] = f2bf(w - bflo(h));
        }
        unsigned short* o = w2l_pk + (size_t)i * 8;
        for (int j = 0; j < 8; ++j) o[j] = v[j];
    }
}

// ---------- MFMA GEMM: hout = act( mean@Wl + bl + hroot@Wr ) ----------
template <int KIN, bool RELU>
__launch_bounds__(256)
__global__ void sage_gemm(const float* __restrict__ meanv,
                          const unsigned short* __restrict__ hroot,
                          const unsigned short* __restrict__ wl_pk,
                          const unsigned short* __restrict__ wr_pk,
                          const float* __restrict__ bl,
                          unsigned short* __restrict__ hout) {
    constexpr int NKS = KIN / 32;
    int wid = threadIdx.x >> 6, lane = threadIdx.x & 63;
    int tile = blockIdx.x * 4 + wid;
    if (tile >= NN / 16) return;
    int m0 = tile * 16;
    int ar = lane & 15;     // A row / D col
    int lg = lane >> 4;

    bf16x8 ah[NKS];
#pragma unroll
    for (int ks = 0; ks < NKS; ++ks)
        ah[ks] = *(const bf16x8*)(hroot + (size_t)(m0 + ar) * KIN + ks * 32 + lg * 8);

    bf16x8 amh[NKS], aml[NKS];
#pragma unroll
    for (int ks = 0; ks < NKS; ++ks) {
        const float* p = meanv + (size_t)(m0 + ar) * KIN + ks * 32 + lg * 8;
        float4 v0 = *(const float4*)p;
        float4 v1 = *(const float4*)(p + 4);
        float mv[8] = {v0.x, v0.y, v0.z, v0.w, v1.x, v1.y, v1.z, v1.w};
#pragma unroll
        for (int j = 0; j < 8; ++j) {
            unsigned short h = f2bf(mv[j]);
            amh[ks][j] = (short)h;
            aml[ks][j] = (short)f2bf(mv[j] - bflo(h));
        }
    }

#pragma unroll
    for (int nt = 0; nt < 4; ++nt) {
        f32x4 acc = {0.f, 0.f, 0.f, 0.f};
#pragma unroll
        for (int ks = 0; ks < NKS; ++ks) {
            int fi = ks * 4 + nt;
            bf16x8 wlh = *(const bf16x8*)(wl_pk + ((size_t)(fi * 2 + 0) * 64 + lane) * 8);
            bf16x8 wll = *(const bf16x8*)(wl_pk + ((size_t)(fi * 2 + 1) * 64 + lane) * 8);
            bf16x8 wrh = *(const bf16x8*)(wr_pk + ((size_t)(fi * 2 + 0) * 64 + lane) * 8);
            bf16x8 wrl = *(const bf16x8*)(wr_pk + ((size_t)(fi * 2 + 1) * 64 + lane) * 8);
            acc = __builtin_amdgcn_mfma_f32_16x16x32_bf16(amh[ks], wlh, acc, 0, 0, 0);
            acc = __builtin_amdgcn_mfma_f32_16x16x32_bf16(amh[ks], wll, acc, 0, 0, 0);
            acc = __builtin_amdgcn_mfma_f32_16x16x32_bf16(aml[ks], wlh, acc, 0, 0, 0);
            acc = __builtin_amdgcn_mfma_f32_16x16x32_bf16(ah[ks],  wrh, acc, 0, 0, 0);
            acc = __builtin_amdgcn_mfma_f32_16x16x32_bf16(ah[ks],  wrl, acc, 0, 0, 0);
        }
        float b = bl[nt * 16 + ar];
#pragma unroll
        for (int r = 0; r < 4; ++r) {
            float o = acc[r] + b;
            if (RELU) o = fmaxf(o, 0.f);
            hout[(size_t)(m0 + lg * 4 + r) * 64 + nt * 16 + ar] = f2bf(o);
        }
    }
}

// ---------- a1/a2 = h2 @ W1[0:64], h2 @ W1[64:128] ----------
__launch_bounds__(256)
__global__ void pred_gemm(const unsigned short* __restrict__ h2,
                          const unsigned short* __restrict__ wa_pk,
                          const unsigned short* __restrict__ wb_pk,
                          unsigned short* __restrict__ a1,
                          unsigned short* __restrict__ a2) {
    int wid = threadIdx.x >> 6, lane = threadIdx.x & 63;
    int tile = blockIdx.x * 4 + wid;
    if (tile >= NN / 16) return;
    int m0 = tile * 16;
    int ar = lane & 15;
    int lg = lane >> 4;
    bf16x8 ah[2];
#pragma unroll
    for (int ks = 0; ks < 2; ++ks)
        ah[ks] = *(const bf16x8*)(h2 + (size_t)(m0 + ar) * 64 + ks * 32 + lg * 8);
#pragma unroll
    for (int nt = 0; nt < 4; ++nt) {
        f32x4 p = {0.f, 0.f, 0.f, 0.f};
        f32x4 q = {0.f, 0.f, 0.f, 0.f};
#pragma unroll
        for (int ks = 0; ks < 2; ++ks) {
            int fi = ks * 4 + nt;
            bf16x8 wah = *(const bf16x8*)(wa_pk + ((size_t)(fi * 2 + 0) * 64 + lane) * 8);
            bf16x8 wal = *(const bf16x8*)(wa_pk + ((size_t)(fi * 2 + 1) * 64 + lane) * 8);
            bf16x8 wbh = *(const bf16x8*)(wb_pk + ((size_t)(fi * 2 + 0) * 64 + lane) * 8);
            bf16x8 wbl = *(const bf16x8*)(wb_pk + ((size_t)(fi * 2 + 1) * 64 + lane) * 8);
            p = __builtin_amdgcn_mfma_f32_16x16x32_bf16(ah[ks], wah, p, 0, 0, 0);
            p = __builtin_amdgcn_mfma_f32_16x16x32_bf16(ah[ks], wal, p, 0, 0, 0);
            q = __builtin_amdgcn_mfma_f32_16x16x32_bf16(ah[ks], wbh, q, 0, 0, 0);
            q = __builtin_amdgcn_mfma_f32_16x16x32_bf16(ah[ks], wbl, q, 0, 0, 0);
        }
#pragma unroll
        for (int r = 0; r < 4; ++r) {
            size_t off = (size_t)(m0 + lg * 4 + r) * 64 + nt * 16 + ar;
            a1[off] = f2bf(p[r]);
            a2[off] = f2bf(q[r]);
        }
    }
}

// ---------- edge predictor: transposed MFMA pipeline, 16 edges per wave ----------
// z1^T[f][e] = we_pk @ ea_pk  (C layout: lane holds f = ks*16+lg*4+q, e = lane&15)
// + a1[s] + a2[d] gathered in exactly that layout -> relu -> half-filled B-frags
// z2^T = w2_pk @ relu(z1)^T (hi/lo), z3 via VALU + shfl reduce over lg.
__launch_bounds__(256)
__global__ void edge_pred(const int* __restrict__ src, const int* __restrict__ dst,
                          const unsigned short* __restrict__ a1, const unsigned short* __restrict__ a2,
                          const float* __restrict__ ea,
                          const unsigned short* __restrict__ we_pk,
                          const unsigned short* __restrict__ w2h_pk,
                          const unsigned short* __restrict__ w2l_pk,
                          const float* __restrict__ W3, const float* __restrict__ b3,
                          float* __restrict__ out) {
    int wid = threadIdx.x >> 6, lane = threadIdx.x & 63;
    int tile = blockIdx.x * 4 + wid;        // 100000 tiles exactly
    int e0 = tile * 16;
    int ar = lane & 15, lg = lane >> 4;
    int e = e0 + ar;

    int s = src[e];
    int d = dst[e];

    // B-frag of packed ea^T (K=32): lg0/2 = ea_hi, lg1 = ea_lo, lg3 = {1,1,0..} (bias rows)
    const float4* ep = (const float4*)(ea + (size_t)e * 8);
    float4 f0 = ep[0], f1 = ep[1];
    float ev[8] = {f0.x, f0.y, f0.z, f0.w, f1.x, f1.y, f1.z, f1.w};
    bf16x8 bea = {0, 0, 0, 0, 0, 0, 0, 0};
    if (lg == 3) {
        bea[0] = (short)0x3F80; bea[1] = (short)0x3F80;
    } else if (lg == 1) {
#pragma unroll
        for (int j = 0; j < 8; ++j) {
            unsigned short h = f2bf(ev[j]);
            bea[j] = (short)f2bf(ev[j] - bflo(h));
        }
    } else {
#pragma unroll
        for (int j = 0; j < 8; ++j) bea[j] = (short)f2bf(ev[j]);
    }

    // gather endpoint fragments early (independent of MFMA)
    uint2 ua[4], ub[4];
#pragma unroll
    for (int ks = 0; ks < 4; ++ks) {
        ua[ks] = *(const uint2*)(a1 + (size_t)s * 64 + ks * 16 + lg * 4);
        ub[ks] = *(const uint2*)(a2 + (size_t)d * 64 + ks * 16 + lg * 4);
    }

    // z1^T = we_pk @ bea : 4 feature-tiles
    f32x4 accE[4];
#pragma unroll
    for (int mt = 0; mt < 4; ++mt) {
        bf16x8 aw = *(const bf16x8*)(we_pk + ((size_t)(mt * 64 + lane)) * 8);
        f32x4 z = {0.f, 0.f, 0.f, 0.f};
        accE[mt] = __builtin_amdgcn_mfma_f32_16x16x32_bf16(aw, bea, z, 0, 0, 0);
    }

    // add gathers, relu, build half-filled B-frags, z2 MFMAs
    f32x4 acc2[2] = {{0.f, 0.f, 0.f, 0.f}, {0.f, 0.f, 0.f, 0.f}};
#pragma unroll
    for (int ks = 0; ks < 4; ++ks) {
        float z0 = accE[ks][0] + bflo(ua[ks].x) + bflo(ub[ks].x);
        float z1 = accE[ks][1] + bfhi(ua[ks].x) + bfhi(ub[ks].x);
        float z2 = accE[ks][2] + bflo(ua[ks].y) + bflo(ub[ks].y);
        float z3 = accE[ks][3] + bfhi(ua[ks].y) + bfhi(ub[ks].y);
        z0 = fmaxf(z0, 0.f); z1 = fmaxf(z1, 0.f);
        z2 = fmaxf(z2, 0.f); z3 = fmaxf(z3, 0.f);
        unsigned short h0 = f2bf(z0), h1 = f2bf(z1), h2 = f2bf(z2), h3 = f2bf(z3);
        bf16x8 zh = {(short)h0, (short)h1, (short)h2, (short)h3, 0, 0, 0, 0};
        bf16x8 zl = {(short)f2bf(z0 - bflo(h0)), (short)f2bf(z1 - bflo(h1)),
                     (short)f2bf(z2 - bflo(h2)), (short)f2bf(z3 - bflo(h3)), 0, 0, 0, 0};
#pragma unroll
        for (int mt2 = 0; mt2 < 2; ++mt2) {
            bf16x8 Ah = *(const bf16x8*)(w2h_pk + ((size_t)((mt2 * 5 + ks) * 64 + lane)) * 8);
            bf16x8 Al = *(const bf16x8*)(w2l_pk + ((size_t)((mt2 * 4 + ks) * 64 + lane)) * 8);
            acc2[mt2] = __builtin_amdgcn_mfma_f32_16x16x32_bf16(Ah, zh, acc2[mt2], 0, 0, 0);
            acc2[mt2] = __builtin_amdgcn_mfma_f32_16x16x32_bf16(Ah, zl, acc2[mt2], 0, 0, 0);
            acc2[mt2] = __builtin_amdgcn_mfma_f32_16x16x32_bf16(Al, zh, acc2[mt2], 0, 0, 0);
        }
    }
    // bias tile (k rows 0,1 of ks=4 weight tile hold b2_hi/b2_lo)
    {
        bf16x8 bone = {0, 0, 0, 0, 0, 0, 0, 0};
        if (lg == 0) { bone[0] = (short)0x3F80; bone[1] = (short)0x3F80; }
#pragma unroll
        for (int mt2 = 0; mt2 < 2; ++mt2) {
            bf16x8 Ah = *(const bf16x8*)(w2h_pk + ((size_t)((mt2 * 5 + 4) * 64 + lane)) * 8);
            acc2[mt2] = __builtin_amdgcn_mfma_f32_16x16x32_bf16(Ah, bone, acc2[mt2], 0, 0, 0);
        }
    }

    // z3 = relu(z2) @ W3 : partial over this lane's 8 W2-cols, reduce across lg
    float p = 0.f;
#pragma unroll
    for (int mt2 = 0; mt2 < 2; ++mt2) {
        float4 w3 = *(const float4*)(W3 + mt2 * 16 + lg * 4);
        p = fmaf(fmaxf(acc2[mt2][0], 0.f), w3.x, p);
        p = fmaf(fmaxf(acc2[mt2][1], 0.f), w3.y, p);
        p = fmaf(fmaxf(acc2[mt2][2], 0.f), w3.z, p);
        p = fmaf(fmaxf(acc2[mt2][3], 0.f), w3.w, p);
    }
    p += __shfl_xor(p, 16);
    p += __shfl_xor(p, 32);
    if (lane < 16) {
        float o = p + b3[0];
        out[e] = 1.0f / (1.0f + __expf(-o));
    }
}

extern "C" void kernel_launch(void* const* d_in, const int* in_sizes, int n_in,
                              void* d_out, int out_size, void* d_ws, size_t ws_size,
                              hipStream_t stream) {
    const float* x   = (const float*)d_in[0];
    const int*   ei  = (const int*)d_in[1];
    const float* ea  = (const float*)d_in[2];
    const float* Wl0 = (const float*)d_in[3];
    const float* bl0 = (const float*)d_in[4];
    const float* Wr0 = (const float*)d_in[5];
    const float* Wl1 = (const float*)d_in[6];
    const float* bl1 = (const float*)d_in[7];
    const float* Wr1 = (const float*)d_in[8];
    const float* Wl2 = (const float*)d_in[9];
    const float* bl2 = (const float*)d_in[10];
    const float* Wr2 = (const float*)d_in[11];
    const float* W1  = (const float*)d_in[12];
    const float* b1  = (const float*)d_in[13];
    const float* W2  = (const float*)d_in[14];
    const float* b2  = (const float*)d_in[15];
    const float* W3  = (const float*)d_in[16];
    const float* b3  = (const float*)d_in[17];

    const int* src = ei;
    const int* dst = ei + NE;

    char* ws = (char*)d_ws;
    size_t off = 0;
    auto alloc = [&](size_t bytes) {
        void* p = ws + off;
        off += (bytes + 255) & ~(size_t)255;
        return p;
    };
    unsigned short* xb = (unsigned short*)alloc((size_t)NN * 32 * 2);
    unsigned short* hA = (unsigned short*)alloc((size_t)NN * HID * 2);  // layer0 out; reused as h2
    unsigned short* hB = (unsigned short*)alloc((size_t)NN * HID * 2);  // layer1 out
    unsigned short* a1 = (unsigned short*)alloc((size_t)NN * HID * 2);
    unsigned short* a2 = (unsigned short*)alloc((size_t)NN * HID * 2);
    unsigned short* wpk = (unsigned short*)alloc((size_t)68608 * 2);
    int* degI    = (int*)alloc(NN * sizeof(int));
    int* row_ptr = (int*)alloc(NN * sizeof(int));
    int* rowtmp  = (int*)alloc(NN * sizeof(int));
    int* cursor  = (int*)alloc(NN * sizeof(int));
    int* blockSum= (int*)alloc(512 * sizeof(int));
    int* blockOff= (int*)alloc(512 * sizeof(int));
    int* csr_src = (int*)alloc((size_t)NE * sizeof(int));
    // meanv aliases [a1|a2] (25.6MB): all mean reads complete before pred_gemm writes a1/a2
    float* meanv = (float*)a1;
    float* out = (float*)d_out;

    // packed edge-predictor weight offsets (in shorts)
    unsigned short* we_pk  = wpk + 57344;   // 2048
    unsigned short* w2h_pk = wpk + 59392;   // 5120
    unsigned short* w2l_pk = wpk + 64512;   // 4096

    const int BS = 256;
    dim3 blkE((NE + BS - 1) / BS);
    int n4 = NN * 32 / 4;
    int gemm_blk = (NN / 16 + 3) / 4;   // 1563

    // ---- x -> bf16 + CSR build + weight prep ----
    hipMemsetAsync(degI, 0, NN * sizeof(int), stream);
    hipMemsetAsync(cursor, 0, NN * sizeof(int), stream);
    xcast<<<(n4 + BS - 1) / BS, BS, 0, stream>>>(x, xb, n4);
    count_kernel<<<blkE, BS, 0, stream>>>(dst, degI, NE);
    scan1_kernel<<<NBLK, SCAN_BS, 0, stream>>>(degI, rowtmp, blockSum);
    scan2_kernel<<<1, 512, 0, stream>>>(blockSum, blockOff, NBLK);
    scan3_kernel<<<NBLK, SCAN_BS, 0, stream>>>(rowtmp, blockOff, row_ptr);
    fill_kernel<<<blkE, BS, 0, stream>>>(src, dst, row_ptr, cursor, csr_src, NE);
    wprep<<<14, 256, 0, stream>>>(Wl0, Wr0, Wl1, Wr1, Wl2, Wr2, W1, wpk);
    wprep2<<<1, 256, 0, stream>>>(W1, b1, W2, b2, we_pk, w2h_pk, w2l_pk);

    // ---- layer 0 ----
    aggregate<32><<<NN / 4, 256, 0, stream>>>(row_ptr, degI, csr_src, xb, meanv);
    sage_gemm<32, true><<<gemm_blk, 256, 0, stream>>>(meanv, xb, wpk + 0, wpk + 4096, bl0, hA);
    // ---- layer 1 ----
    aggregate<64><<<NN / 4, 256, 0, stream>>>(row_ptr, degI, csr_src, hA, meanv);
    sage_gemm<64, true><<<gemm_blk, 256, 0, stream>>>(meanv, hA, wpk + 8192, wpk + 16384, bl1, hB);
    // ---- layer 2 (no ReLU) ----
    aggregate<64><<<NN / 4, 256, 0, stream>>>(row_ptr, degI, csr_src, hB, meanv);
    sage_gemm<64, false><<<gemm_blk, 256, 0, stream>>>(meanv, hB, wpk + 24576, wpk + 32768, bl2, hA);
    // ---- a1/a2 = h2 @ W1 halves ----
    pred_gemm<<<gemm_blk, 256, 0, stream>>>(hA, wpk + 40960, wpk + 49152, a1, a2);

    // ---- edge predictor (MFMA, 16 edges/wave, 25000 blocks x 4 waves) ----
    edge_pred<<<NE / 64, BS, 0, stream>>>(src, dst, a1, a2, ea, we_pk, w2h_pk, w2l_pk, W3, b3, out);
}

// Round 3
// 631.717 us; speedup vs baseline: 1.0022x; 1.0022x over previous
//
#include <hip/hip_runtime.h>
#include <hip/hip_bf16.h>

#define NN 100000
#define NE 1600000
#define HID 64
#define SCAN_BS 256
#define NBLK ((NN + SCAN_BS - 1) / SCAN_BS)   // 391

typedef float f32x4 __attribute__((ext_vector_type(4)));
typedef short bf16x8 __attribute__((ext_vector_type(8)));

__device__ __forceinline__ float bflo(unsigned u) { return __uint_as_float(u << 16); }
__device__ __forceinline__ float bfhi(unsigned u) { return __uint_as_float(u & 0xffff0000u); }
__device__ __forceinline__ unsigned short f2bf(float f) {
    __hip_bfloat16 h = (__hip_bfloat16)f;
    return *(unsigned short*)&h;
}

// ---------- x -> bf16 ----------
__global__ void xcast(const float* __restrict__ in, unsigned short* __restrict__ out, int n4) {
    int i = blockIdx.x * blockDim.x + threadIdx.x;
    if (i >= n4) return;
    float4 v = ((const float4*)in)[i];
    ushort4 o;
    o.x = f2bf(v.x); o.y = f2bf(v.y); o.z = f2bf(v.z); o.w = f2bf(v.w);
    ((ushort4*)out)[i] = o;
}

// ---------- CSR build ----------
__global__ void count_kernel(const int* __restrict__ dst, int* __restrict__ degI, int nE) {
    int e = blockIdx.x * blockDim.x + threadIdx.x;
    if (e < nE) atomicAdd(&degI[dst[e]], 1);
}

__global__ void scan1_kernel(const int* __restrict__ degI, int* __restrict__ rowtmp,
                             int* __restrict__ blockSum) {
    __shared__ int tmp[SCAN_BS];
    int t = threadIdx.x;
    int i = blockIdx.x * SCAN_BS + t;
    int d = (i < NN) ? degI[i] : 0;
    tmp[t] = d;
    __syncthreads();
    for (int off = 1; off < SCAN_BS; off <<= 1) {
        int v = (t >= off) ? tmp[t - off] : 0;
        __syncthreads();
        tmp[t] += v;
        __syncthreads();
    }
    if (i < NN) rowtmp[i] = tmp[t] - d;
    if (t == SCAN_BS - 1) blockSum[blockIdx.x] = tmp[t];
}

__global__ void scan2_kernel(const int* __restrict__ blockSum, int* __restrict__ blockOff, int n) {
    __shared__ int tmp[512];
    int t = threadIdx.x;
    tmp[t] = (t < n) ? blockSum[t] : 0;
    __syncthreads();
    for (int off = 1; off < 512; off <<= 1) {
        int v = (t >= off) ? tmp[t - off] : 0;
        __syncthreads();
        tmp[t] += v;
        __syncthreads();
    }
    if (t < n) blockOff[t] = (t == 0) ? 0 : tmp[t - 1];
}

__global__ void scan3_kernel(const int* __restrict__ rowtmp, const int* __restrict__ blockOff,
                             int* __restrict__ row_ptr) {
    int i = blockIdx.x * SCAN_BS + threadIdx.x;
    if (i < NN) row_ptr[i] = rowtmp[i] + blockOff[blockIdx.x];
}

__global__ void fill_kernel(const int* __restrict__ src, const int* __restrict__ dst,
                            const int* __restrict__ row_ptr, int* __restrict__ cursor,
                            int* __restrict__ csr_src, int nE) {
    int e = blockIdx.x * blockDim.x + threadIdx.x;
    if (e >= nE) return;
    int d = dst[e];
    int pos = atomicAdd(&cursor[d], 1);
    csr_src[row_ptr[d] + pos] = src[e];
}

// ---------- pure gather/mean (one wave per node, shuffle reduce, no LDS) ----------
template <int IN>
__launch_bounds__(256)
__global__ void aggregate(const int* __restrict__ row_ptr, const int* __restrict__ degI,
                          const int* __restrict__ csr_src,
                          const unsigned short* __restrict__ hin,
                          float* __restrict__ mout) {
    constexpr int LPE = IN / 4;            // lanes per edge (uint2 = 4 bf16 each)
    constexpr int SPLIT = 64 / LPE;        // edges in flight per wave
    constexpr int UN = (SPLIT >= 8) ? 2 : 4;
    int g = threadIdx.x >> 6;
    int lane = threadIdx.x & 63;
    int node = blockIdx.x * 4 + g;         // grid sized so node < NN always
    int lane_p = lane & (LPE - 1);
    int sub = lane / LPE;

    float a0 = 0.f, a1 = 0.f, a2 = 0.f, a3 = 0.f;
    int start = row_ptr[node];
    int dg = degI[node];
    const int* cs = csr_src + start;

    int e = sub;
    for (; e + SPLIT * (UN - 1) < dg; e += SPLIT * UN) {
        int sidx[UN];
#pragma unroll
        for (int j = 0; j < UN; ++j) sidx[j] = cs[e + SPLIT * j];
        uint2 u[UN];
#pragma unroll
        for (int j = 0; j < UN; ++j)
            u[j] = *(const uint2*)(hin + (size_t)sidx[j] * IN + 4 * lane_p);
#pragma unroll
        for (int j = 0; j < UN; ++j) {
            a0 += bflo(u[j].x); a1 += bfhi(u[j].x);
            a2 += bflo(u[j].y); a3 += bfhi(u[j].y);
        }
    }
    for (; e < dg; e += SPLIT) {
        uint2 u = *(const uint2*)(hin + (size_t)cs[e] * IN + 4 * lane_p);
        a0 += bflo(u.x); a1 += bfhi(u.x);
        a2 += bflo(u.y); a3 += bfhi(u.y);
    }

    // reduce across the SPLIT sub-groups (lanes LPE apart and up)
#pragma unroll
    for (int m = LPE; m < 64; m <<= 1) {
        a0 += __shfl_xor(a0, m);
        a1 += __shfl_xor(a1, m);
        a2 += __shfl_xor(a2, m);
        a3 += __shfl_xor(a3, m);
    }
    if (sub == 0) {
        float r = 1.0f / fmaxf((float)dg, 1.0f);
        float4 v;
        v.x = a0 * r; v.y = a1 * r; v.z = a2 * r; v.w = a3 * r;
        *(float4*)(mout + (size_t)node * IN + 4 * lane_p) = v;
    }
}

// ---------- weight prep: f32 [K][64] -> packed bf16 hi/lo B-fragments ----------
// layout per matrix: [fi = ks*4+nt][hl][lane][8]  (8 shorts = one uint4 per lane)
// B frag element j of lane l: W[k = ks*32 + (l>>4)*8 + j][n = nt*16 + (l&15)]
__global__ void wprep(const float* __restrict__ Wl0, const float* __restrict__ Wr0,
                      const float* __restrict__ Wl1, const float* __restrict__ Wr1,
                      const float* __restrict__ Wl2, const float* __restrict__ Wr2,
                      const float* __restrict__ W1, unsigned short* __restrict__ out) {
    int b = blockIdx.x;
    int mid, local;
    if (b < 2) { mid = b; local = 0; }                  // K=32 matrices: 1 block each
    else { mid = 2 + (b - 2) / 2; local = (b - 2) & 1; } // K=64 matrices: 2 blocks each
    const float* Ws[8] = {Wl0, Wr0, Wl1, Wr1, Wl2, Wr2, W1, W1 + 64 * 64};
    const int offs[8] = {0, 4096, 8192, 16384, 24576, 32768, 40960, 49152};
    const float* W = Ws[mid];
    int e = local * 256 + threadIdx.x;   // entry = (ks*4+nt)*64 + lane
    int lane = e & 63;
    int fi = e >> 6;                     // ks*4 + nt
    int ks = fi >> 2, nt = fi & 3;
    int lg = lane >> 4, col = lane & 15;
    unsigned short hi[8], lo[8];
#pragma unroll
    for (int j = 0; j < 8; ++j) {
        float w = W[(ks * 32 + lg * 8 + j) * 64 + nt * 16 + col];
        unsigned short h = f2bf(w);
        hi[j] = h;
        lo[j] = f2bf(w - bflo(h));
    }
    unsigned short* dh = out + offs[mid] + ((size_t)(fi * 2 + 0) * 64 + lane) * 8;
    unsigned short* dl = out + offs[mid] + ((size_t)(fi * 2 + 1) * 64 + lane) * 8;
#pragma unroll
    for (int j = 0; j < 8; ++j) { dh[j] = hi[j]; dl[j] = lo[j]; }
}

// ---------- edge-predictor weight prep ----------
// we_pk: A-frags (16x16x32) of [64 feat x 32 K] matrix for z1^T = Wpk @ ea_pk:
//   K rows 0..7 = W1e_hi^T, 8..15 = W1e_hi^T, 16..23 = W1e_lo^T, 24 = b1_hi, 25 = b1_lo.
// w2h_pk/w2l_pk: A-frags (half-filled 16x16x32, j<4 used) of W2^T [32 x 64]:
//   entry ((mt2*NKS+ks)*64+lane)*8: c = mt2*16+(lane&15); j<4 -> W2[ks*16+(lane>>4)*4+j][c].
__global__ void wprep2(const float* __restrict__ W1, const float* __restrict__ b1,
                       const float* __restrict__ W2, const float* __restrict__ b2,
                       unsigned short* __restrict__ we_pk,
                       unsigned short* __restrict__ w2h_pk,
                       unsigned short* __restrict__ w2l_pk) {
    int t = threadIdx.x;          // 256 threads, 1 block
    const float* W1e = W1 + 128 * 64;
    // Part A: we_pk (4 mt x 64 lanes)
    {
        int mt = t >> 6, lane = t & 63;
        int ar = lane & 15, lg = lane >> 4;
        int f = mt * 16 + ar;
        unsigned short v[8];
#pragma unroll
        for (int j = 0; j < 8; ++j) {
            if (lg <= 1) {
                v[j] = f2bf(W1e[j * 64 + f]);
            } else if (lg == 2) {
                float w = W1e[j * 64 + f];
                unsigned short h = f2bf(w);
                v[j] = f2bf(w - bflo(h));
            } else {
                if (j == 0) v[j] = f2bf(b1[f]);
                else if (j == 1) {
                    float bb = b1[f];
                    unsigned short h = f2bf(bb);
                    v[j] = f2bf(bb - bflo(h));
                } else v[j] = 0;
            }
        }
        unsigned short* o = we_pk + (size_t)t * 8;
        for (int j = 0; j < 8; ++j) o[j] = v[j];
    }
    // Part B: w2h_pk (2 mt2 x 5 ks x 64 lanes = 640 entries; ks=4 bias tile kept but unused)
    for (int i = t; i < 640; i += 256) {
        int mt2 = i / 320, rem = i % 320;
        int ks = rem >> 6, lane = rem & 63;
        int ar = lane & 15, lg = lane >> 4;
        int c = mt2 * 16 + ar;
        unsigned short v[8] = {0, 0, 0, 0, 0, 0, 0, 0};
        if (ks < 4) {
            for (int j = 0; j < 4; ++j)
                v[j] = f2bf(W2[(ks * 16 + lg * 4 + j) * 32 + c]);
        } else if (lg == 0) {
            float bb = b2[c];
            unsigned short h = f2bf(bb);
            v[0] = h;
            v[1] = f2bf(bb - bflo(h));
        }
        unsigned short* o = w2h_pk + (size_t)i * 8;
        for (int j = 0; j < 8; ++j) o[j] = v[j];
    }
    // Part C: w2l_pk (2 mt2 x 4 ks x 64 lanes = 512 entries)
    for (int i = t; i < 512; i += 256) {
        int mt2 = i / 256, rem = i % 256;
        int ks = rem >> 6, lane = rem & 63;
        int ar = lane & 15, lg = lane >> 4;
        int c = mt2 * 16 + ar;
        unsigned short v[8] = {0, 0, 0, 0, 0, 0, 0, 0};
        for (int j = 0; j < 4; ++j) {
            float w = W2[(ks * 16 + lg * 4 + j) * 32 + c];
            unsigned short h = f2bf(w);
            v[j] = f2bf(w - bflo(h));
        }
        unsigned short* o = w2l_pk + (size_t)i * 8;
        for (int j = 0; j < 8; ++j) o[j] = v[j];
    }
}

// ---------- MFMA GEMM: hout = act( mean@Wl + bl + hroot@Wr ) ----------
template <int KIN, bool RELU>
__launch_bounds__(256)
__global__ void sage_gemm(const float* __restrict__ meanv,
                          const unsigned short* __restrict__ hroot,
                          const unsigned short* __restrict__ wl_pk,
                          const unsigned short* __restrict__ wr_pk,
                          const float* __restrict__ bl,
                          unsigned short* __restrict__ hout) {
    constexpr int NKS = KIN / 32;
    int wid = threadIdx.x >> 6, lane = threadIdx.x & 63;
    int tile = blockIdx.x * 4 + wid;
    if (tile >= NN / 16) return;
    int m0 = tile * 16;
    int ar = lane & 15;     // A row / D col
    int lg = lane >> 4;

    bf16x8 ah[NKS];
#pragma unroll
    for (int ks = 0; ks < NKS; ++ks)
        ah[ks] = *(const bf16x8*)(hroot + (size_t)(m0 + ar) * KIN + ks * 32 + lg * 8);

    bf16x8 amh[NKS], aml[NKS];
#pragma unroll
    for (int ks = 0; ks < NKS; ++ks) {
        const float* p = meanv + (size_t)(m0 + ar) * KIN + ks * 32 + lg * 8;
        float4 v0 = *(const float4*)p;
        float4 v1 = *(const float4*)(p + 4);
        float mv[8] = {v0.x, v0.y, v0.z, v0.w, v1.x, v1.y, v1.z, v1.w};
#pragma unroll
        for (int j = 0; j < 8; ++j) {
            unsigned short h = f2bf(mv[j]);
            amh[ks][j] = (short)h;
            aml[ks][j] = (short)f2bf(mv[j] - bflo(h));
        }
    }

#pragma unroll
    for (int nt = 0; nt < 4; ++nt) {
        f32x4 acc = {0.f, 0.f, 0.f, 0.f};
#pragma unroll
        for (int ks = 0; ks < NKS; ++ks) {
            int fi = ks * 4 + nt;
            bf16x8 wlh = *(const bf16x8*)(wl_pk + ((size_t)(fi * 2 + 0) * 64 + lane) * 8);
            bf16x8 wll = *(const bf16x8*)(wl_pk + ((size_t)(fi * 2 + 1) * 64 + lane) * 8);
            bf16x8 wrh = *(const bf16x8*)(wr_pk + ((size_t)(fi * 2 + 0) * 64 + lane) * 8);
            bf16x8 wrl = *(const bf16x8*)(wr_pk + ((size_t)(fi * 2 + 1) * 64 + lane) * 8);
            acc = __builtin_amdgcn_mfma_f32_16x16x32_bf16(amh[ks], wlh, acc, 0, 0, 0);
            acc = __builtin_amdgcn_mfma_f32_16x16x32_bf16(amh[ks], wll, acc, 0, 0, 0);
            acc = __builtin_amdgcn_mfma_f32_16x16x32_bf16(aml[ks], wlh, acc, 0, 0, 0);
            acc = __builtin_amdgcn_mfma_f32_16x16x32_bf16(ah[ks],  wrh, acc, 0, 0, 0);
            acc = __builtin_amdgcn_mfma_f32_16x16x32_bf16(ah[ks],  wrl, acc, 0, 0, 0);
        }
        float b = bl[nt * 16 + ar];
#pragma unroll
        for (int r = 0; r < 4; ++r) {
            float o = acc[r] + b;
            if (RELU) o = fmaxf(o, 0.f);
            hout[(size_t)(m0 + lg * 4 + r) * 64 + nt * 16 + ar] = f2bf(o);
        }
    }
}

// ---------- a1/a2 = h2 @ W1[0:64], h2 @ W1[64:128] ----------
__launch_bounds__(256)
__global__ void pred_gemm(const unsigned short* __restrict__ h2,
                          const unsigned short* __restrict__ wa_pk,
                          const unsigned short* __restrict__ wb_pk,
                          unsigned short* __restrict__ a1,
                          unsigned short* __restrict__ a2) {
    int wid = threadIdx.x >> 6, lane = threadIdx.x & 63;
    int tile = blockIdx.x * 4 + wid;
    if (tile >= NN / 16) return;
    int m0 = tile * 16;
    int ar = lane & 15;
    int lg = lane >> 4;
    bf16x8 ah[2];
#pragma unroll
    for (int ks = 0; ks < 2; ++ks)
        ah[ks] = *(const bf16x8*)(h2 + (size_t)(m0 + ar) * 64 + ks * 32 + lg * 8);
#pragma unroll
    for (int nt = 0; nt < 4; ++nt) {
        f32x4 p = {0.f, 0.f, 0.f, 0.f};
        f32x4 q = {0.f, 0.f, 0.f, 0.f};
#pragma unroll
        for (int ks = 0; ks < 2; ++ks) {
            int fi = ks * 4 + nt;
            bf16x8 wah = *(const bf16x8*)(wa_pk + ((size_t)(fi * 2 + 0) * 64 + lane) * 8);
            bf16x8 wal = *(const bf16x8*)(wa_pk + ((size_t)(fi * 2 + 1) * 64 + lane) * 8);
            bf16x8 wbh = *(const bf16x8*)(wb_pk + ((size_t)(fi * 2 + 0) * 64 + lane) * 8);
            bf16x8 wbl = *(const bf16x8*)(wb_pk + ((size_t)(fi * 2 + 1) * 64 + lane) * 8);
            p = __builtin_amdgcn_mfma_f32_16x16x32_bf16(ah[ks], wah, p, 0, 0, 0);
            p = __builtin_amdgcn_mfma_f32_16x16x32_bf16(ah[ks], wal, p, 0, 0, 0);
            q = __builtin_amdgcn_mfma_f32_16x16x32_bf16(ah[ks], wbh, q, 0, 0, 0);
            q = __builtin_amdgcn_mfma_f32_16x16x32_bf16(ah[ks], wbl, q, 0, 0, 0);
        }
#pragma unroll
        for (int r = 0; r < 4; ++r) {
            size_t off = (size_t)(m0 + lg * 4 + r) * 64 + nt * 16 + ar;
            a1[off] = f2bf(p[r]);
            a2[off] = f2bf(q[r]);
        }
    }
}

// ---------- edge predictor: transposed MFMA pipeline, 4 tiles (64 edges) per wave ----------
// All long-latency loads (src/dst, a1/a2 gathers, ea) for 64 edges issued up front;
// per-tile MFMA math identical to the 1-tile version; b2 folded in as f32 VALU add.
__launch_bounds__(256)
__global__ void edge_pred(const int* __restrict__ src, const int* __restrict__ dst,
                          const unsigned short* __restrict__ a1, const unsigned short* __restrict__ a2,
                          const float* __restrict__ ea,
                          const unsigned short* __restrict__ we_pk,
                          const unsigned short* __restrict__ w2h_pk,
                          const unsigned short* __restrict__ w2l_pk,
                          const float* __restrict__ W3, const float* __restrict__ b3,
                          const float* __restrict__ b2,
                          float* __restrict__ out) {
    constexpr int TPW = 4;
    int wid = threadIdx.x >> 6, lane = threadIdx.x & 63;
    int ar = lane & 15, lg = lane >> 4;
    int tile0 = (blockIdx.x * 4 + wid) * TPW;

    // ---- issue all long-latency loads up front (64 edges in flight per wave) ----
    int ei_[TPW], s_[TPW], d_[TPW];
#pragma unroll
    for (int t = 0; t < TPW; ++t) {
        int e = (tile0 + t) * 16 + ar;
        ei_[t] = e;
        s_[t] = src[e];
        d_[t] = dst[e];
    }
    uint2 ua[TPW][4], ub[TPW][4];
#pragma unroll
    for (int t = 0; t < TPW; ++t) {
        const unsigned short* pa = a1 + (size_t)s_[t] * 64 + lg * 4;
        const unsigned short* pb = a2 + (size_t)d_[t] * 64 + lg * 4;
#pragma unroll
        for (int ks = 0; ks < 4; ++ks) {
            ua[t][ks] = *(const uint2*)(pa + ks * 16);
            ub[t][ks] = *(const uint2*)(pb + ks * 16);
        }
    }
    float4 ef0[TPW], ef1[TPW];
#pragma unroll
    for (int t = 0; t < TPW; ++t) {
        const float4* ep = (const float4*)(ea + (size_t)ei_[t] * 8);
        ef0[t] = ep[0];
        ef1[t] = ep[1];
    }

    // loop-invariant fragments / constants
    bf16x8 aw[4];
#pragma unroll
    for (int mt = 0; mt < 4; ++mt)
        aw[mt] = *(const bf16x8*)(we_pk + ((size_t)(mt * 64 + lane)) * 8);
    float4 b2v0 = *(const float4*)(b2 + lg * 4);
    float4 b2v1 = *(const float4*)(b2 + 16 + lg * 4);
    float4 w3a = *(const float4*)(W3 + lg * 4);
    float4 w3b = *(const float4*)(W3 + 16 + lg * 4);

    float pz[TPW];
#pragma unroll
    for (int t = 0; t < TPW; ++t) {
        // pack ea -> B-frag (K=32 rows: lg0/2 = ea_hi, lg1 = ea_lo, lg3 = bias ones)
        float evv[8] = {ef0[t].x, ef0[t].y, ef0[t].z, ef0[t].w,
                        ef1[t].x, ef1[t].y, ef1[t].z, ef1[t].w};
        bf16x8 bea = {0, 0, 0, 0, 0, 0, 0, 0};
        if (lg == 3) {
            bea[0] = (short)0x3F80; bea[1] = (short)0x3F80;
        } else if (lg == 1) {
#pragma unroll
            for (int j = 0; j < 8; ++j) {
                unsigned short h = f2bf(evv[j]);
                bea[j] = (short)f2bf(evv[j] - bflo(h));
            }
        } else {
#pragma unroll
            for (int j = 0; j < 8; ++j) bea[j] = (short)f2bf(evv[j]);
        }

        // z1^T = we_pk @ bea
        f32x4 accE[4];
#pragma unroll
        for (int mt = 0; mt < 4; ++mt) {
            f32x4 z = {0.f, 0.f, 0.f, 0.f};
            accE[mt] = __builtin_amdgcn_mfma_f32_16x16x32_bf16(aw[mt], bea, z, 0, 0, 0);
        }

        // add gathers, relu, half-filled B-frags, z2 MFMAs
        f32x4 acc2[2] = {{0.f, 0.f, 0.f, 0.f}, {0.f, 0.f, 0.f, 0.f}};
#pragma unroll
        for (int ks = 0; ks < 4; ++ks) {
            float z0 = accE[ks][0] + bflo(ua[t][ks].x) + bflo(ub[t][ks].x);
            float z1 = accE[ks][1] + bfhi(ua[t][ks].x) + bfhi(ub[t][ks].x);
            float z2 = accE[ks][2] + bflo(ua[t][ks].y) + bflo(ub[t][ks].y);
            float z3 = accE[ks][3] + bfhi(ua[t][ks].y) + bfhi(ub[t][ks].y);
            z0 = fmaxf(z0, 0.f); z1 = fmaxf(z1, 0.f);
            z2 = fmaxf(z2, 0.f); z3 = fmaxf(z3, 0.f);
            unsigned short h0 = f2bf(z0), h1 = f2bf(z1), h2 = f2bf(z2), h3 = f2bf(z3);
            bf16x8 zh = {(short)h0, (short)h1, (short)h2, (short)h3, 0, 0, 0, 0};
            bf16x8 zl = {(short)f2bf(z0 - bflo(h0)), (short)f2bf(z1 - bflo(h1)),
                         (short)f2bf(z2 - bflo(h2)), (short)f2bf(z3 - bflo(h3)), 0, 0, 0, 0};
#pragma unroll
            for (int mt2 = 0; mt2 < 2; ++mt2) {
                bf16x8 Ah = *(const bf16x8*)(w2h_pk + ((size_t)((mt2 * 5 + ks) * 64 + lane)) * 8);
                bf16x8 Al = *(const bf16x8*)(w2l_pk + ((size_t)((mt2 * 4 + ks) * 64 + lane)) * 8);
                acc2[mt2] = __builtin_amdgcn_mfma_f32_16x16x32_bf16(Ah, zh, acc2[mt2], 0, 0, 0);
                acc2[mt2] = __builtin_amdgcn_mfma_f32_16x16x32_bf16(Ah, zl, acc2[mt2], 0, 0, 0);
                acc2[mt2] = __builtin_amdgcn_mfma_f32_16x16x32_bf16(Al, zh, acc2[mt2], 0, 0, 0);
            }
        }

        // z3 partial: b2 added in f32, relu, dot with this lane's 8 W3 entries
        float p = 0.f;
        p = fmaf(fmaxf(acc2[0][0] + b2v0.x, 0.f), w3a.x, p);
        p = fmaf(fmaxf(acc2[0][1] + b2v0.y, 0.f), w3a.y, p);
        p = fmaf(fmaxf(acc2[0][2] + b2v0.z, 0.f), w3a.z, p);
        p = fmaf(fmaxf(acc2[0][3] + b2v0.w, 0.f), w3a.w, p);
        p = fmaf(fmaxf(acc2[1][0] + b2v1.x, 0.f), w3b.x, p);
        p = fmaf(fmaxf(acc2[1][1] + b2v1.y, 0.f), w3b.y, p);
        p = fmaf(fmaxf(acc2[1][2] + b2v1.z, 0.f), w3b.z, p);
        p = fmaf(fmaxf(acc2[1][3] + b2v1.w, 0.f), w3b.w, p);
        p += __shfl_xor(p, 16);
        p += __shfl_xor(p, 32);
        pz[t] = p;
    }

    float bb3 = b3[0];
#pragma unroll
    for (int t = 0; t < TPW; ++t) {
        if (lane < 16)
            out[ei_[t]] = 1.0f / (1.0f + __expf(-(pz[t] + bb3)));
    }
}

extern "C" void kernel_launch(void* const* d_in, const int* in_sizes, int n_in,
                              void* d_out, int out_size, void* d_ws, size_t ws_size,
                              hipStream_t stream) {
    const float* x   = (const float*)d_in[0];
    const int*   ei  = (const int*)d_in[1];
    const float* ea  = (const float*)d_in[2];
    const float* Wl0 = (const float*)d_in[3];
    const float* bl0 = (const float*)d_in[4];
    const float* Wr0 = (const float*)d_in[5];
    const float* Wl1 = (const float*)d_in[6];
    const float* bl1 = (const float*)d_in[7];
    const float* Wr1 = (const float*)d_in[8];
    const float* Wl2 = (const float*)d_in[9];
    const float* bl2 = (const float*)d_in[10];
    const float* Wr2 = (const float*)d_in[11];
    const float* W1  = (const float*)d_in[12];
    const float* b1  = (const float*)d_in[13];
    const float* W2  = (const float*)d_in[14];
    const float* b2  = (const float*)d_in[15];
    const float* W3  = (const float*)d_in[16];
    const float* b3  = (const float*)d_in[17];

    const int* src = ei;
    const int* dst = ei + NE;

    char* ws = (char*)d_ws;
    size_t off = 0;
    auto alloc = [&](size_t bytes) {
        void* p = ws + off;
        off += (bytes + 255) & ~(size_t)255;
        return p;
    };
    unsigned short* xb = (unsigned short*)alloc((size_t)NN * 32 * 2);
    unsigned short* hA = (unsigned short*)alloc((size_t)NN * HID * 2);  // layer0 out; reused as h2
    unsigned short* hB = (unsigned short*)alloc((size_t)NN * HID * 2);  // layer1 out
    unsigned short* a1 = (unsigned short*)alloc((size_t)NN * HID * 2);
    unsigned short* a2 = (unsigned short*)alloc((size_t)NN * HID * 2);
    unsigned short* wpk = (unsigned short*)alloc((size_t)68608 * 2);
    int* degI    = (int*)alloc(NN * sizeof(int));
    int* row_ptr = (int*)alloc(NN * sizeof(int));
    int* rowtmp  = (int*)alloc(NN * sizeof(int));
    int* cursor  = (int*)alloc(NN * sizeof(int));
    int* blockSum= (int*)alloc(512 * sizeof(int));
    int* blockOff= (int*)alloc(512 * sizeof(int));
    int* csr_src = (int*)alloc((size_t)NE * sizeof(int));
    // meanv aliases [a1|a2] (25.6MB): all mean reads complete before pred_gemm writes a1/a2
    float* meanv = (float*)a1;
    float* out = (float*)d_out;

    // packed edge-predictor weight offsets (in shorts)
    unsigned short* we_pk  = wpk + 57344;   // 2048
    unsigned short* w2h_pk = wpk + 59392;   // 5120
    unsigned short* w2l_pk = wpk + 64512;   // 4096

    const int BS = 256;
    dim3 blkE((NE + BS - 1) / BS);
    int n4 = NN * 32 / 4;
    int gemm_blk = (NN / 16 + 3) / 4;   // 1563

    // ---- x -> bf16 + CSR build + weight prep ----
    hipMemsetAsync(degI, 0, NN * sizeof(int), stream);
    hipMemsetAsync(cursor, 0, NN * sizeof(int), stream);
    xcast<<<(n4 + BS - 1) / BS, BS, 0, stream>>>(x, xb, n4);
    count_kernel<<<blkE, BS, 0, stream>>>(dst, degI, NE);
    scan1_kernel<<<NBLK, SCAN_BS, 0, stream>>>(degI, rowtmp, blockSum);
    scan2_kernel<<<1, 512, 0, stream>>>(blockSum, blockOff, NBLK);
    scan3_kernel<<<NBLK, SCAN_BS, 0, stream>>>(rowtmp, blockOff, row_ptr);
    fill_kernel<<<blkE, BS, 0, stream>>>(src, dst, row_ptr, cursor, csr_src, NE);
    wprep<<<14, 256, 0, stream>>>(Wl0, Wr0, Wl1, Wr1, Wl2, Wr2, W1, wpk);
    wprep2<<<1, 256, 0, stream>>>(W1, b1, W2, b2, we_pk, w2h_pk, w2l_pk);

    // ---- layer 0 ----
    aggregate<32><<<NN / 4, 256, 0, stream>>>(row_ptr, degI, csr_src, xb, meanv);
    sage_gemm<32, true><<<gemm_blk, 256, 0, stream>>>(meanv, xb, wpk + 0, wpk + 4096, bl0, hA);
    // ---- layer 1 ----
    aggregate<64><<<NN / 4, 256, 0, stream>>>(row_ptr, degI, csr_src, hA, meanv);
    sage_gemm<64, true><<<gemm_blk, 256, 0, stream>>>(meanv, hA, wpk + 8192, wpk + 16384, bl1, hB);
    // ---- layer 2 (no ReLU) ----
    aggregate<64><<<NN / 4, 256, 0, stream>>>(row_ptr, degI, csr_src, hB, meanv);
    sage_gemm<64, false><<<gemm_blk, 256, 0, stream>>>(meanv, hB, wpk + 24576, wpk + 32768, bl2, hA);
    // ---- a1/a2 = h2 @ W1 halves ----
    pred_gemm<<<gemm_blk, 256, 0, stream>>>(hA, wpk + 40960, wpk + 49152, a1, a2);

    // ---- edge predictor (MFMA, 64 edges/wave, 6250 blocks x 4 waves) ----
    edge_pred<<<NE / 256, BS, 0, stream>>>(src, dst, a1, a2, ea, we_pk, w2h_pk, w2l_pk, W3, b3, b2, out);
}

// Round 4
// 556.542 us; speedup vs baseline: 1.1375x; 1.1351x over previous
//
#include <hip/hip_runtime.h>
#include <hip/hip_bf16.h>

#define NN 100000
#define NE 1600000
#define HID 64
#define SCAN_BS 256
#define NBLK ((NN + SCAN_BS - 1) / SCAN_BS)   // 391

typedef float f32x4 __attribute__((ext_vector_type(4)));
typedef short bf16x8 __attribute__((ext_vector_type(8)));

__device__ __forceinline__ float bflo(unsigned u) { return __uint_as_float(u << 16); }
__device__ __forceinline__ float bfhi(unsigned u) { return __uint_as_float(u & 0xffff0000u); }
__device__ __forceinline__ unsigned short f2bf(float f) {
    __hip_bfloat16 h = (__hip_bfloat16)f;
    return *(unsigned short*)&h;
}

// ---------- x -> bf16 ----------
__global__ void xcast(const float* __restrict__ in, unsigned short* __restrict__ out, int n4) {
    int i = blockIdx.x * blockDim.x + threadIdx.x;
    if (i >= n4) return;
    float4 v = ((const float4*)in)[i];
    ushort4 o;
    o.x = f2bf(v.x); o.y = f2bf(v.y); o.z = f2bf(v.z); o.w = f2bf(v.w);
    ((ushort4*)out)[i] = o;
}

// ---------- CSR build ----------
__global__ void count_kernel(const int* __restrict__ dst, int* __restrict__ degI, int nE) {
    int e = blockIdx.x * blockDim.x + threadIdx.x;
    if (e < nE) atomicAdd(&degI[dst[e]], 1);
}

__global__ void scan1_kernel(const int* __restrict__ degI, int* __restrict__ rowtmp,
                             int* __restrict__ blockSum) {
    __shared__ int tmp[SCAN_BS];
    int t = threadIdx.x;
    int i = blockIdx.x * SCAN_BS + t;
    int d = (i < NN) ? degI[i] : 0;
    tmp[t] = d;
    __syncthreads();
    for (int off = 1; off < SCAN_BS; off <<= 1) {
        int v = (t >= off) ? tmp[t - off] : 0;
        __syncthreads();
        tmp[t] += v;
        __syncthreads();
    }
    if (i < NN) rowtmp[i] = tmp[t] - d;
    if (t == SCAN_BS - 1) blockSum[blockIdx.x] = tmp[t];
}

__global__ void scan2_kernel(const int* __restrict__ blockSum, int* __restrict__ blockOff, int n) {
    __shared__ int tmp[512];
    int t = threadIdx.x;
    tmp[t] = (t < n) ? blockSum[t] : 0;
    __syncthreads();
    for (int off = 1; off < 512; off <<= 1) {
        int v = (t >= off) ? tmp[t - off] : 0;
        __syncthreads();
        tmp[t] += v;
        __syncthreads();
    }
    if (t < n) blockOff[t] = (t == 0) ? 0 : tmp[t - 1];
}

__global__ void scan3_kernel(const int* __restrict__ rowtmp, const int* __restrict__ blockOff,
                             int* __restrict__ row_ptr) {
    int i = blockIdx.x * SCAN_BS + threadIdx.x;
    if (i < NN) row_ptr[i] = rowtmp[i] + blockOff[blockIdx.x];
}

__global__ void fill_kernel(const int* __restrict__ src, const int* __restrict__ dst,
                            const int* __restrict__ row_ptr, int* __restrict__ cursor,
                            int* __restrict__ csr_src, int nE) {
    int e = blockIdx.x * blockDim.x + threadIdx.x;
    if (e >= nE) return;
    int d = dst[e];
    int pos = atomicAdd(&cursor[d], 1);
    csr_src[row_ptr[d] + pos] = src[e];
}

// ---------- pure gather/mean (one wave per node, uint4 loads, shuffle reduce) ----------
// LPE = IN/8 lanes cover one row (uint4 = 8 bf16 = 16 B per lane).
// IN=64: SPLIT=8 edges in flight, UN=2 -> 16 edges per main iter (= avg degree).
// IN=32: SPLIT=16, UN=1 -> 16 edges per iter.
template <int IN>
__launch_bounds__(256)
__global__ void aggregate(const int* __restrict__ row_ptr, const int* __restrict__ degI,
                          const int* __restrict__ csr_src,
                          const unsigned short* __restrict__ hin,
                          float* __restrict__ mout) {
    constexpr int LPE = IN / 8;
    constexpr int SPLIT = 64 / LPE;
    constexpr int UN = (IN == 64) ? 2 : 1;
    int g = threadIdx.x >> 6;
    int lane = threadIdx.x & 63;
    int node = blockIdx.x * 4 + g;         // grid sized so node < NN always
    int lane_p = lane & (LPE - 1);
    int sub = lane / LPE;

    float acc[8];
#pragma unroll
    for (int i = 0; i < 8; ++i) acc[i] = 0.f;

    int start = row_ptr[node];
    int dg = degI[node];
    const int* cs = csr_src + start;

    int e = sub;
    for (; e + SPLIT * (UN - 1) < dg; e += SPLIT * UN) {
        uint4 u[UN];
#pragma unroll
        for (int j = 0; j < UN; ++j) {
            int s = cs[e + SPLIT * j];
            u[j] = *(const uint4*)(hin + (size_t)s * IN + 8 * lane_p);
        }
#pragma unroll
        for (int j = 0; j < UN; ++j) {
            acc[0] += bflo(u[j].x); acc[1] += bfhi(u[j].x);
            acc[2] += bflo(u[j].y); acc[3] += bfhi(u[j].y);
            acc[4] += bflo(u[j].z); acc[5] += bfhi(u[j].z);
            acc[6] += bflo(u[j].w); acc[7] += bfhi(u[j].w);
        }
    }
    for (; e < dg; e += SPLIT) {
        int s = cs[e];
        uint4 u = *(const uint4*)(hin + (size_t)s * IN + 8 * lane_p);
        acc[0] += bflo(u.x); acc[1] += bfhi(u.x);
        acc[2] += bflo(u.y); acc[3] += bfhi(u.y);
        acc[4] += bflo(u.z); acc[5] += bfhi(u.z);
        acc[6] += bflo(u.w); acc[7] += bfhi(u.w);
    }

    // reduce across the SPLIT sub-groups (lanes LPE apart and up)
#pragma unroll
    for (int m = LPE; m < 64; m <<= 1) {
#pragma unroll
        for (int i = 0; i < 8; ++i) acc[i] += __shfl_xor(acc[i], m);
    }
    if (sub == 0) {
        float r = 1.0f / fmaxf((float)dg, 1.0f);
        float4 v0, v1;
        v0.x = acc[0] * r; v0.y = acc[1] * r; v0.z = acc[2] * r; v0.w = acc[3] * r;
        v1.x = acc[4] * r; v1.y = acc[5] * r; v1.z = acc[6] * r; v1.w = acc[7] * r;
        float* p = mout + (size_t)node * IN + 8 * lane_p;
        *(float4*)p = v0;
        *(float4*)(p + 4) = v1;
    }
}

// ---------- weight prep: f32 [K][64] -> packed bf16 hi/lo B-fragments ----------
// layout per matrix: [fi = ks*4+nt][hl][lane][8]  (8 shorts = one uint4 per lane)
// B frag element j of lane l: W[k = ks*32 + (l>>4)*8 + j][n = nt*16 + (l&15)]
__global__ void wprep(const float* __restrict__ Wl0, const float* __restrict__ Wr0,
                      const float* __restrict__ Wl1, const float* __restrict__ Wr1,
                      const float* __restrict__ Wl2, const float* __restrict__ Wr2,
                      const float* __restrict__ W1, unsigned short* __restrict__ out) {
    int b = blockIdx.x;
    int mid, local;
    if (b < 2) { mid = b; local = 0; }                  // K=32 matrices: 1 block each
    else { mid = 2 + (b - 2) / 2; local = (b - 2) & 1; } // K=64 matrices: 2 blocks each
    const float* Ws[8] = {Wl0, Wr0, Wl1, Wr1, Wl2, Wr2, W1, W1 + 64 * 64};
    const int offs[8] = {0, 4096, 8192, 16384, 24576, 32768, 40960, 49152};
    const float* W = Ws[mid];
    int e = local * 256 + threadIdx.x;   // entry = (ks*4+nt)*64 + lane
    int lane = e & 63;
    int fi = e >> 6;                     // ks*4 + nt
    int ks = fi >> 2, nt = fi & 3;
    int lg = lane >> 4, col = lane & 15;
    unsigned short hi[8], lo[8];
#pragma unroll
    for (int j = 0; j < 8; ++j) {
        float w = W[(ks * 32 + lg * 8 + j) * 64 + nt * 16 + col];
        unsigned short h = f2bf(w);
        hi[j] = h;
        lo[j] = f2bf(w - bflo(h));
    }
    unsigned short* dh = out + offs[mid] + ((size_t)(fi * 2 + 0) * 64 + lane) * 8;
    unsigned short* dl = out + offs[mid] + ((size_t)(fi * 2 + 1) * 64 + lane) * 8;
#pragma unroll
    for (int j = 0; j < 8; ++j) { dh[j] = hi[j]; dl[j] = lo[j]; }
}

// ---------- MFMA GEMM: hout = act( mean@Wl + bl + hroot@Wr ) ----------
template <int KIN, bool RELU>
__launch_bounds__(256)
__global__ void sage_gemm(const float* __restrict__ meanv,
                          const unsigned short* __restrict__ hroot,
                          const unsigned short* __restrict__ wl_pk,
                          const unsigned short* __restrict__ wr_pk,
                          const float* __restrict__ bl,
                          unsigned short* __restrict__ hout) {
    constexpr int NKS = KIN / 32;
    int wid = threadIdx.x >> 6, lane = threadIdx.x & 63;
    int tile = blockIdx.x * 4 + wid;
    if (tile >= NN / 16) return;
    int m0 = tile * 16;
    int ar = lane & 15;     // A row / D col
    int lg = lane >> 4;

    bf16x8 ah[NKS];
#pragma unroll
    for (int ks = 0; ks < NKS; ++ks)
        ah[ks] = *(const bf16x8*)(hroot + (size_t)(m0 + ar) * KIN + ks * 32 + lg * 8);

    bf16x8 amh[NKS], aml[NKS];
#pragma unroll
    for (int ks = 0; ks < NKS; ++ks) {
        const float* p = meanv + (size_t)(m0 + ar) * KIN + ks * 32 + lg * 8;
        float4 v0 = *(const float4*)p;
        float4 v1 = *(const float4*)(p + 4);
        float mv[8] = {v0.x, v0.y, v0.z, v0.w, v1.x, v1.y, v1.z, v1.w};
#pragma unroll
        for (int j = 0; j < 8; ++j) {
            unsigned short h = f2bf(mv[j]);
            amh[ks][j] = (short)h;
            aml[ks][j] = (short)f2bf(mv[j] - bflo(h));
        }
    }

#pragma unroll
    for (int nt = 0; nt < 4; ++nt) {
        f32x4 acc = {0.f, 0.f, 0.f, 0.f};
#pragma unroll
        for (int ks = 0; ks < NKS; ++ks) {
            int fi = ks * 4 + nt;
            bf16x8 wlh = *(const bf16x8*)(wl_pk + ((size_t)(fi * 2 + 0) * 64 + lane) * 8);
            bf16x8 wll = *(const bf16x8*)(wl_pk + ((size_t)(fi * 2 + 1) * 64 + lane) * 8);
            bf16x8 wrh = *(const bf16x8*)(wr_pk + ((size_t)(fi * 2 + 0) * 64 + lane) * 8);
            bf16x8 wrl = *(const bf16x8*)(wr_pk + ((size_t)(fi * 2 + 1) * 64 + lane) * 8);
            acc = __builtin_amdgcn_mfma_f32_16x16x32_bf16(amh[ks], wlh, acc, 0, 0, 0);
            acc = __builtin_amdgcn_mfma_f32_16x16x32_bf16(amh[ks], wll, acc, 0, 0, 0);
            acc = __builtin_amdgcn_mfma_f32_16x16x32_bf16(aml[ks], wlh, acc, 0, 0, 0);
            acc = __builtin_amdgcn_mfma_f32_16x16x32_bf16(ah[ks],  wrh, acc, 0, 0, 0);
            acc = __builtin_amdgcn_mfma_f32_16x16x32_bf16(ah[ks],  wrl, acc, 0, 0, 0);
        }
        float b = bl[nt * 16 + ar];
#pragma unroll
        for (int r = 0; r < 4; ++r) {
            float o = acc[r] + b;
            if (RELU) o = fmaxf(o, 0.f);
            hout[(size_t)(m0 + lg * 4 + r) * 64 + nt * 16 + ar] = f2bf(o);
        }
    }
}

// ---------- a1/a2 = h2 @ W1[0:64], h2 @ W1[64:128] ----------
__launch_bounds__(256)
__global__ void pred_gemm(const unsigned short* __restrict__ h2,
                          const unsigned short* __restrict__ wa_pk,
                          const unsigned short* __restrict__ wb_pk,
                          unsigned short* __restrict__ a1,
                          unsigned short* __restrict__ a2) {
    int wid = threadIdx.x >> 6, lane = threadIdx.x & 63;
    int tile = blockIdx.x * 4 + wid;
    if (tile >= NN / 16) return;
    int m0 = tile * 16;
    int ar = lane & 15;
    int lg = lane >> 4;
    bf16x8 ah[2];
#pragma unroll
    for (int ks = 0; ks < 2; ++ks)
        ah[ks] = *(const bf16x8*)(h2 + (size_t)(m0 + ar) * 64 + ks * 32 + lg * 8);
#pragma unroll
    for (int nt = 0; nt < 4; ++nt) {
        f32x4 p = {0.f, 0.f, 0.f, 0.f};
        f32x4 q = {0.f, 0.f, 0.f, 0.f};
#pragma unroll
        for (int ks = 0; ks < 2; ++ks) {
            int fi = ks * 4 + nt;
            bf16x8 wah = *(const bf16x8*)(wa_pk + ((size_t)(fi * 2 + 0) * 64 + lane) * 8);
            bf16x8 wal = *(const bf16x8*)(wa_pk + ((size_t)(fi * 2 + 1) * 64 + lane) * 8);
            bf16x8 wbh = *(const bf16x8*)(wb_pk + ((size_t)(fi * 2 + 0) * 64 + lane) * 8);
            bf16x8 wbl = *(const bf16x8*)(wb_pk + ((size_t)(fi * 2 + 1) * 64 + lane) * 8);
            p = __builtin_amdgcn_mfma_f32_16x16x32_bf16(ah[ks], wah, p, 0, 0, 0);
            p = __builtin_amdgcn_mfma_f32_16x16x32_bf16(ah[ks], wal, p, 0, 0, 0);
            q = __builtin_amdgcn_mfma_f32_16x16x32_bf16(ah[ks], wbh, q, 0, 0, 0);
            q = __builtin_amdgcn_mfma_f32_16x16x32_bf16(ah[ks], wbl, q, 0, 0, 0);
        }
#pragma unroll
        for (int r = 0; r < 4; ++r) {
            size_t off = (size_t)(m0 + lg * 4 + r) * 64 + nt * 16 + ar;
            a1[off] = f2bf(p[r]);
            a2[off] = f2bf(q[r]);
        }
    }
}

// ---------- edge predictor (R1 VALU version: one edge per lane, 64 in flight/wave) ----------
__launch_bounds__(256)
__global__ void edge_pred(const int* __restrict__ src, const int* __restrict__ dst,
                          const unsigned short* __restrict__ a1, const unsigned short* __restrict__ a2,
                          const float* __restrict__ ea,
                          const float* __restrict__ W1, const float* __restrict__ b1,
                          const float* __restrict__ W2, const float* __restrict__ b2,
                          const float* __restrict__ W3, const float* __restrict__ b3,
                          float* __restrict__ out, int nE) {
    int e = blockIdx.x * blockDim.x + threadIdx.x;
    if (e >= nE) return;
    int s = src[e];
    int d = dst[e];

    const uint4* pa = (const uint4*)(a1 + (size_t)s * 64);
    const uint4* pb = (const uint4*)(a2 + (size_t)d * 64);
    const float4* eav = (const float4*)(ea + (size_t)e * 8);
    float4 v0 = eav[0];
    float4 v1 = eav[1];

    float z1[64];
    const float* wr = W1 + 128 * 64;
#pragma unroll
    for (int j = 0; j < 64; ++j) {
        float a = fmaf(v0.x, wr[j], b1[j]);
        a = fmaf(v0.y, wr[64 + j], a);
        a = fmaf(v0.z, wr[128 + j], a);
        a = fmaf(v0.w, wr[192 + j], a);
        a = fmaf(v1.x, wr[256 + j], a);
        a = fmaf(v1.y, wr[320 + j], a);
        a = fmaf(v1.z, wr[384 + j], a);
        z1[j] = fmaf(v1.w, wr[448 + j], a);
    }

#pragma unroll
    for (int q = 0; q < 8; ++q) {
        uint4 ua = pa[q];
        uint4 ub = pb[q];
        int j0 = q * 8;
        z1[j0 + 0] += bflo(ua.x) + bflo(ub.x);
        z1[j0 + 1] += bfhi(ua.x) + bfhi(ub.x);
        z1[j0 + 2] += bflo(ua.y) + bflo(ub.y);
        z1[j0 + 3] += bfhi(ua.y) + bfhi(ub.y);
        z1[j0 + 4] += bflo(ua.z) + bflo(ub.z);
        z1[j0 + 5] += bfhi(ua.z) + bfhi(ub.z);
        z1[j0 + 6] += bflo(ua.w) + bflo(ub.w);
        z1[j0 + 7] += bfhi(ua.w) + bfhi(ub.w);
    }

    float z2[32];
#pragma unroll
    for (int j = 0; j < 32; ++j) z2[j] = b2[j];
    for (int k = 0; k < 64; ++k) {
        float v = fmaxf(z1[k], 0.0f);
        const float* w = W2 + (size_t)k * 32;
#pragma unroll
        for (int j = 0; j < 32; ++j) z2[j] = fmaf(v, w[j], z2[j]);
    }

    float o = b3[0];
#pragma unroll
    for (int k = 0; k < 32; ++k) o = fmaf(fmaxf(z2[k], 0.0f), W3[k], o);

    out[e] = 1.0f / (1.0f + __expf(-o));
}

extern "C" void kernel_launch(void* const* d_in, const int* in_sizes, int n_in,
                              void* d_out, int out_size, void* d_ws, size_t ws_size,
                              hipStream_t stream) {
    const float* x   = (const float*)d_in[0];
    const int*   ei  = (const int*)d_in[1];
    const float* ea  = (const float*)d_in[2];
    const float* Wl0 = (const float*)d_in[3];
    const float* bl0 = (const float*)d_in[4];
    const float* Wr0 = (const float*)d_in[5];
    const float* Wl1 = (const float*)d_in[6];
    const float* bl1 = (const float*)d_in[7];
    const float* Wr1 = (const float*)d_in[8];
    const float* Wl2 = (const float*)d_in[9];
    const float* bl2 = (const float*)d_in[10];
    const float* Wr2 = (const float*)d_in[11];
    const float* W1  = (const float*)d_in[12];
    const float* b1  = (const float*)d_in[13];
    const float* W2  = (const float*)d_in[14];
    const float* b2  = (const float*)d_in[15];
    const float* W3  = (const float*)d_in[16];
    const float* b3  = (const float*)d_in[17];

    const int* src = ei;
    const int* dst = ei + NE;

    char* ws = (char*)d_ws;
    size_t off = 0;
    auto alloc = [&](size_t bytes) {
        void* p = ws + off;
        off += (bytes + 255) & ~(size_t)255;
        return p;
    };
    unsigned short* xb = (unsigned short*)alloc((size_t)NN * 32 * 2);
    unsigned short* hA = (unsigned short*)alloc((size_t)NN * HID * 2);  // layer0 out; reused as h2
    unsigned short* hB = (unsigned short*)alloc((size_t)NN * HID * 2);  // layer1 out
    unsigned short* a1 = (unsigned short*)alloc((size_t)NN * HID * 2);
    unsigned short* a2 = (unsigned short*)alloc((size_t)NN * HID * 2);
    unsigned short* wpk = (unsigned short*)alloc((size_t)57344 * 2);
    int* degI    = (int*)alloc(NN * sizeof(int));
    int* row_ptr = (int*)alloc(NN * sizeof(int));
    int* rowtmp  = (int*)alloc(NN * sizeof(int));
    int* cursor  = (int*)alloc(NN * sizeof(int));
    int* blockSum= (int*)alloc(512 * sizeof(int));
    int* blockOff= (int*)alloc(512 * sizeof(int));
    int* csr_src = (int*)alloc((size_t)NE * sizeof(int));
    // meanv aliases [a1|a2] (25.6MB): all mean reads complete before pred_gemm writes a1/a2
    float* meanv = (float*)a1;
    float* out = (float*)d_out;

    const int BS = 256;
    dim3 blkE((NE + BS - 1) / BS);
    int n4 = NN * 32 / 4;
    int gemm_blk = (NN / 16 + 3) / 4;   // 1563

    // ---- x -> bf16 + CSR build + weight prep ----
    hipMemsetAsync(degI, 0, NN * sizeof(int), stream);
    hipMemsetAsync(cursor, 0, NN * sizeof(int), stream);
    xcast<<<(n4 + BS - 1) / BS, BS, 0, stream>>>(x, xb, n4);
    count_kernel<<<blkE, BS, 0, stream>>>(dst, degI, NE);
    scan1_kernel<<<NBLK, SCAN_BS, 0, stream>>>(degI, rowtmp, blockSum);
    scan2_kernel<<<1, 512, 0, stream>>>(blockSum, blockOff, NBLK);
    scan3_kernel<<<NBLK, SCAN_BS, 0, stream>>>(rowtmp, blockOff, row_ptr);
    fill_kernel<<<blkE, BS, 0, stream>>>(src, dst, row_ptr, cursor, csr_src, NE);
    wprep<<<14, 256, 0, stream>>>(Wl0, Wr0, Wl1, Wr1, Wl2, Wr2, W1, wpk);

    // ---- layer 0 ----
    aggregate<32><<<NN / 4, 256, 0, stream>>>(row_ptr, degI, csr_src, xb, meanv);
    sage_gemm<32, true><<<gemm_blk, 256, 0, stream>>>(meanv, xb, wpk + 0, wpk + 4096, bl0, hA);
    // ---- layer 1 ----
    aggregate<64><<<NN / 4, 256, 0, stream>>>(row_ptr, degI, csr_src, hA, meanv);
    sage_gemm<64, true><<<gemm_blk, 256, 0, stream>>>(meanv, hA, wpk + 8192, wpk + 16384, bl1, hB);
    // ---- layer 2 (no ReLU) ----
    aggregate<64><<<NN / 4, 256, 0, stream>>>(row_ptr, degI, csr_src, hB, meanv);
    sage_gemm<64, false><<<gemm_blk, 256, 0, stream>>>(meanv, hB, wpk + 24576, wpk + 32768, bl2, hA);
    // ---- a1/a2 = h2 @ W1 halves ----
    pred_gemm<<<gemm_blk, 256, 0, stream>>>(hA, wpk + 40960, wpk + 49152, a1, a2);

    // ---- edge predictor (VALU, one edge per lane) ----
    edge_pred<<<blkE, BS, 0, stream>>>(src, dst, a1, a2, ea, W1, b1, W2, b2, W3, b3, out, NE);
}